// Round 1
// baseline (1198.798 us; speedup 1.0000x reference)
//
#include <hip/hip_runtime.h>

// ---------------------------------------------------------------------------
// SelfAttention fused pipeline for MI355X (gfx950)
//   x(4,1024,2048) f32; Wq(2048,2048) Wk/Wv(2048,512) Wp(2048,2048) f32
//   out = proj(attn(rope(q),rope(k),v)) , all GEMMs in bf16 MFMA (fp32 accum)
// ---------------------------------------------------------------------------

typedef __attribute__((ext_vector_type(4))) float f32x4;
typedef __attribute__((ext_vector_type(8))) short short8;

#define AS1C(p) ((const __attribute__((address_space(1))) void*)(p))
#define AS3(p)  ((__attribute__((address_space(3))) void*)(p))

__device__ __forceinline__ unsigned short f2bf(float f) {
  union { float f; unsigned int u; } x; x.f = f;
  unsigned int r = x.u + 0x7FFFu + ((x.u >> 16) & 1u);  // round-to-nearest-even
  return (unsigned short)(r >> 16);
}

// -------------------- x : f32 -> bf16 (vectorized) -------------------------
__global__ void cvt_bf16_kernel(const float* __restrict__ src,
                                unsigned short* __restrict__ dst, int n4) {
  int i = blockIdx.x * blockDim.x + threadIdx.x;
  if (i >= n4) return;
  const f32x4 v = *(const f32x4*)(src + (size_t)i * 4);
  ushort4 u = make_ushort4(f2bf(v[0]), f2bf(v[1]), f2bf(v[2]), f2bf(v[3]));
  *(ushort4*)(dst + (size_t)i * 4) = u;
}

// ------ W transpose+convert: dst[(rowOff+n)*2048 + k] = bf16(src[k*N+n]) ----
__global__ void transpose_bf16_kernel(const float* __restrict__ src,
                                      unsigned short* __restrict__ dst,
                                      int N, int rowOff) {
  __shared__ float tile[32][33];
  const int n0 = blockIdx.x * 32, k0 = blockIdx.y * 32;
  const int tx = threadIdx.x & 31, ty = threadIdx.x >> 5;  // 32x8
#pragma unroll
  for (int i = ty; i < 32; i += 8)
    tile[i][tx] = src[(size_t)(k0 + i) * N + (n0 + tx)];
  __syncthreads();
#pragma unroll
  for (int i = ty; i < 32; i += 8)
    dst[(size_t)(rowOff + n0 + i) * 2048 + (k0 + tx)] = f2bf(tile[tx][i]);
}

// -------------------- bf16 MFMA GEMM: C = A * Bt^T --------------------------
// A: [M][K] bf16 row-major (lda=K), Bt: [N][K] bf16 (row n = col n of W)
// C: [M][N] f32.  128x128 tile, BK=64, 4 waves (2x2), 16x16x32 MFMA.
// LDS staged via global_load_lds (linear dest) with XOR-involution swizzle
// applied to the GLOBAL source granule and to the ds_read slot (rule #21).
// Both A and B fragments use the same assumed k-map -> permutation-invariant.
__global__ __launch_bounds__(256) void gemm_bf16_kernel(
    const unsigned short* __restrict__ A, const unsigned short* __restrict__ Bt,
    float* __restrict__ C, int K, int N) {
  __shared__ unsigned short As[128 * 64];
  __shared__ unsigned short Bs[128 * 64];
  const int tid = threadIdx.x;
  const int lane = tid & 63, wid = tid >> 6;
  const int m0 = blockIdx.y * 128, n0 = blockIdx.x * 128;
  const int wm = (wid >> 1) * 64, wn = (wid & 1) * 64;
  const int l15 = lane & 15, lg = lane >> 4;

  f32x4 acc[4][4];
#pragma unroll
  for (int i = 0; i < 4; ++i)
#pragma unroll
    for (int j = 0; j < 4; ++j)
#pragma unroll
      for (int c = 0; c < 4; ++c) acc[i][j][c] = 0.0f;

  for (int kt = 0; kt < K; kt += 64) {
    __syncthreads();  // previous compute done before overwriting LDS
#pragma unroll
    for (int it = 0; it < 4; ++it) {
      const int chunk = it * 4 + wid;        // 16 chunks of 64 granules (16B)
      const int gi = chunk * 64 + lane;      // granule 0..1023
      const int r = gi >> 3, sg = gi & 7;    // row 0..127, slot 0..7
      const int ks = kt + ((sg ^ (r & 7)) << 3);  // pre-swizzled source
      __builtin_amdgcn_global_load_lds(AS1C(A + (size_t)(m0 + r) * K + ks),
                                       AS3(&As[chunk * 512]), 16, 0, 0);
      __builtin_amdgcn_global_load_lds(AS1C(Bt + (size_t)(n0 + r) * K + ks),
                                       AS3(&Bs[chunk * 512]), 16, 0, 0);
    }
    __syncthreads();  // drains vmcnt
#pragma unroll
    for (int kk = 0; kk < 2; ++kk) {
      short8 av[4], bv[4];
#pragma unroll
      for (int f = 0; f < 4; ++f) {
        const int ra = wm + f * 16 + l15;
        av[f] = *(const short8*)&As[ra * 64 + ((((kk << 2) | lg) ^ (ra & 7)) << 3)];
        const int rb = wn + f * 16 + l15;
        bv[f] = *(const short8*)&Bs[rb * 64 + ((((kk << 2) | lg) ^ (rb & 7)) << 3)];
      }
#pragma unroll
      for (int fm = 0; fm < 4; ++fm)
#pragma unroll
        for (int fn = 0; fn < 4; ++fn)
          acc[fm][fn] = __builtin_amdgcn_mfma_f32_16x16x32_bf16(
              av[fm], bv[fn], acc[fm][fn], 0, 0, 0);
    }
  }
  // C/D layout (m89-verified): col = lane&15, row = (lane>>4)*4 + reg
  const int cr = lg << 2;
#pragma unroll
  for (int fm = 0; fm < 4; ++fm)
#pragma unroll
    for (int fn = 0; fn < 4; ++fn) {
      const size_t base =
          (size_t)(m0 + wm + fm * 16 + cr) * N + (n0 + wn + fn * 16 + l15);
#pragma unroll
      for (int r = 0; r < 4; ++r) C[base + (size_t)r * N] = acc[fm][fn][r];
    }
}

// -------------------- RoPE in-place on Q (cols 0..2047) + K (2048..2559) ----
__global__ void rope_kernel(float* __restrict__ qkv) {
  const int idx = blockIdx.x * 256 + threadIdx.x;  // 4096*1280 threads
  const int m = idx / 1280;
  const int p = idx - m * 1280;
  const int t = m & 1023;
  int i, col;
  if (p < 1024) {               // Q: 32 heads * 32 pairs
    i = p & 31; col = ((p >> 5) << 6) + (i << 1);
  } else {                      // K: 8 heads * 32 pairs
    const int pk = p - 1024;
    i = pk & 31; col = 2048 + ((pk >> 5) << 6) + (i << 1);
  }
  const float inv = powf(10000.0f, -(float)i * (1.0f / 32.0f));
  const float ang = (float)t * inv;
  float sv, cv;
  sincosf(ang, &sv, &cv);
  float* ptr = qkv + (size_t)m * 3072 + col;
  const float x1 = ptr[0], x2 = ptr[1];
  ptr[0] = x1 * cv - x2 * sv;   // q[2i]*cos - q[2i+1]*sin
  ptr[1] = x2 * cv + x1 * sv;   // q[2i+1]*cos + q[2i]*sin
}

// -------------------- fp32 flash attention (causal, GQA 4:1) ---------------
// block = (qt, h, b); 64 q-rows x 64-wide kv tiles; 16x16 thread grid,
// 4x4 microtile per thread. LDS float4-granule swizzle g ^ ((r+(r>>2))&15)
// keeps every read/write pattern <=2-way bank aliased.
__device__ __forceinline__ int sw32(int r, int g) {
  return r * 64 + ((g ^ ((r + (r >> 2)) & 15)) << 2);
}

__global__ __launch_bounds__(256) void attn_kernel(
    const float* __restrict__ qkv, unsigned short* __restrict__ attnb) {
  const int qt = blockIdx.x, h = blockIdx.y, b = blockIdx.z;
  const int kvh = h >> 2;
  __shared__ float Qs[4096], KVs[4096], Ps[4096];
  const int tid = threadIdx.x;
  const int tr = tid >> 4, tc = tid & 15;
  const int tr4 = tr << 2, tc4 = tc << 2;
  const size_t qrow0 = (size_t)b * 1024 + (size_t)qt * 64;

  // stage Q tile (head h, RoPE already applied)
#pragma unroll
  for (int it = 0; it < 4; ++it) {
    const int gl = it * 256 + tid, r = gl >> 4, g = gl & 15;
    const f32x4 v = *(const f32x4*)&qkv[(qrow0 + r) * 3072 + h * 64 + g * 4];
    *(f32x4*)&Qs[sw32(r, g)] = v;
  }

  float m_i[4], l_i[4], o[4][4];
#pragma unroll
  for (int i = 0; i < 4; ++i) {
    m_i[i] = -INFINITY; l_i[i] = 0.f;
#pragma unroll
    for (int j = 0; j < 4; ++j) o[i][j] = 0.f;
  }

  for (int jt = 0; jt <= qt; ++jt) {
    __syncthreads();  // prev PV done reading V; (1st iter: nothing pending)
    // stage K tile (RoPE'd)
#pragma unroll
    for (int it = 0; it < 4; ++it) {
      const int gl = it * 256 + tid, r = gl >> 4, g = gl & 15;
      const f32x4 v = *(const f32x4*)&qkv[((size_t)b * 1024 + jt * 64 + r) * 3072
                                          + 2048 + kvh * 64 + g * 4];
      *(f32x4*)&KVs[sw32(r, g)] = v;
    }
    __syncthreads();  // K (and Q on first iter) visible

    // S = Q K^T
    float s[4][4];
#pragma unroll
    for (int i = 0; i < 4; ++i)
#pragma unroll
      for (int j = 0; j < 4; ++j) s[i][j] = 0.f;
#pragma unroll
    for (int kb = 0; kb < 16; ++kb) {
      f32x4 qr[4], kr[4];
#pragma unroll
      for (int i = 0; i < 4; ++i) qr[i] = *(const f32x4*)&Qs[sw32(tr4 + i, kb)];
#pragma unroll
      for (int j = 0; j < 4; ++j) kr[j] = *(const f32x4*)&KVs[sw32(tc4 + j, kb)];
#pragma unroll
      for (int i = 0; i < 4; ++i)
#pragma unroll
        for (int j = 0; j < 4; ++j) {
          s[i][j] += qr[i][0] * kr[j][0];
          s[i][j] += qr[i][1] * kr[j][1];
          s[i][j] += qr[i][2] * kr[j][2];
          s[i][j] += qr[i][3] * kr[j][3];
        }
    }

    // scale + causal mask + online softmax; write P
    const bool diag = (jt == qt);
#pragma unroll
    for (int i = 0; i < 4; ++i) {
      const int row = tr4 + i;
      float rm = -INFINITY;
#pragma unroll
      for (int j = 0; j < 4; ++j) {
        float v = s[i][j] * 0.125f;
        if (diag && (tc4 + j) > row) v = -INFINITY;
        s[i][j] = v;
        rm = fmaxf(rm, v);
      }
      rm = fmaxf(rm, __shfl_xor(rm, 1));
      rm = fmaxf(rm, __shfl_xor(rm, 2));
      rm = fmaxf(rm, __shfl_xor(rm, 4));
      rm = fmaxf(rm, __shfl_xor(rm, 8));
      const float mn = fmaxf(m_i[i], rm);
      const float alpha = __expf(m_i[i] - mn);  // exp(-inf)=0 on 1st tile
      m_i[i] = mn;
      float rs = 0.f;
      f32x4 pv;
#pragma unroll
      for (int j = 0; j < 4; ++j) {
        const float pj = __expf(s[i][j] - mn);
        pv[j] = pj; rs += pj;
      }
      rs += __shfl_xor(rs, 1);
      rs += __shfl_xor(rs, 2);
      rs += __shfl_xor(rs, 4);
      rs += __shfl_xor(rs, 8);
      l_i[i] = l_i[i] * alpha + rs;
#pragma unroll
      for (int j = 0; j < 4; ++j) o[i][j] *= alpha;
      *(f32x4*)&Ps[sw32(row, tc)] = pv;
    }
    __syncthreads();  // done reading K, P fully written

    // stage V tile over K's buffer
#pragma unroll
    for (int it = 0; it < 4; ++it) {
      const int gl = it * 256 + tid, r = gl >> 4, g = gl & 15;
      const f32x4 v = *(const f32x4*)&qkv[((size_t)b * 1024 + jt * 64 + r) * 3072
                                          + 2560 + kvh * 64 + g * 4];
      *(f32x4*)&KVs[sw32(r, g)] = v;
    }
    __syncthreads();

    // O += P V
#pragma unroll
    for (int kb = 0; kb < 16; ++kb) {
      f32x4 pr[4], vr[4];
#pragma unroll
      for (int i = 0; i < 4; ++i) pr[i] = *(const f32x4*)&Ps[sw32(tr4 + i, kb)];
#pragma unroll
      for (int kk = 0; kk < 4; ++kk)
        vr[kk] = *(const f32x4*)&KVs[sw32(kb * 4 + kk, tc)];
#pragma unroll
      for (int i = 0; i < 4; ++i)
#pragma unroll
        for (int kk = 0; kk < 4; ++kk)
#pragma unroll
          for (int j = 0; j < 4; ++j) o[i][j] += pr[i][kk] * vr[kk][j];
    }
  }

  // epilogue: normalize, write bf16 [4096][2048] at col h*64
#pragma unroll
  for (int i = 0; i < 4; ++i) {
    const float inv = 1.0f / l_i[i];
    ushort4 u = make_ushort4(f2bf(o[i][0] * inv), f2bf(o[i][1] * inv),
                             f2bf(o[i][2] * inv), f2bf(o[i][3] * inv));
    *(ushort4*)&attnb[(qrow0 + tr4 + i) * 2048 + h * 64 + tc4] = u;
  }
}

// ---------------------------------------------------------------------------
extern "C" void kernel_launch(void* const* d_in, const int* in_sizes, int n_in,
                              void* d_out, int out_size, void* d_ws, size_t ws_size,
                              hipStream_t stream) {
  (void)in_sizes; (void)n_in; (void)out_size; (void)ws_size;
  const float* x  = (const float*)d_in[0];
  const float* Wq = (const float*)d_in[1];
  const float* Wk = (const float*)d_in[2];
  const float* Wv = (const float*)d_in[3];
  const float* Wp = (const float*)d_in[4];

  // workspace layout (bytes): 104,857,600 total
  char* w = (char*)d_ws;
  unsigned short* xb    = (unsigned short*)(w);              // 16 MiB  x bf16
  unsigned short* Wt    = (unsigned short*)(w + 16777216);   // 12 MiB  [3072][2048] = [Wq|Wk|Wv]^T
  unsigned short* Wpt   = (unsigned short*)(w + 29360128);   //  8 MiB  Wp^T
  float*          qkv   = (float*)(w + 37748736);            // 48 MiB  [4096][3072] f32
  unsigned short* attnb = (unsigned short*)(w + 88080384);   // 16 MiB  attn out bf16
  float* out = (float*)d_out;

  cvt_bf16_kernel<<<8192, 256, 0, stream>>>(x, xb, 2097152);
  transpose_bf16_kernel<<<dim3(64, 64), 256, 0, stream>>>(Wq, Wt, 2048, 0);
  transpose_bf16_kernel<<<dim3(16, 64), 256, 0, stream>>>(Wk, Wt, 512, 2048);
  transpose_bf16_kernel<<<dim3(16, 64), 256, 0, stream>>>(Wv, Wt, 512, 2560);
  transpose_bf16_kernel<<<dim3(64, 64), 256, 0, stream>>>(Wp, Wpt, 2048, 0);

  // QKV projection: [4096][2048] x [2048][3072] -> qkv f32
  gemm_bf16_kernel<<<dim3(24, 32), 256, 0, stream>>>(xb, Wt, qkv, 2048, 3072);
  rope_kernel<<<20480, 256, 0, stream>>>(qkv);
  attn_kernel<<<dim3(16, 32, 4), 256, 0, stream>>>(qkv, attnb);
  // output projection: [4096][2048] x [2048][2048] -> d_out f32
  gemm_bf16_kernel<<<dim3(16, 32), 256, 0, stream>>>(attnb, Wpt, out, 2048, 2048);
}

// Round 2
// 279.550 us; speedup vs baseline: 4.2883x; 4.2883x over previous
//
#include <hip/hip_runtime.h>

// ---------------------------------------------------------------------------
// SelfAttention fused pipeline for MI355X (gfx950)
//   x(4,1024,2048) f32; Wq(2048,2048) Wk/Wv(2048,512) Wp(2048,2048) f32
//   GEMMs + attention QK^T/PV in bf16 MFMA (fp32 accum), RoPE/softmax in f32.
// ---------------------------------------------------------------------------

typedef __attribute__((ext_vector_type(4))) float f32x4;
typedef __attribute__((ext_vector_type(8))) short short8;

#define AS1C(p) ((const __attribute__((address_space(1))) void*)(p))
#define AS3(p)  ((__attribute__((address_space(3))) void*)(p))

__device__ __forceinline__ unsigned short f2bf(float f) {
  union { float f; unsigned int u; } x; x.f = f;
  unsigned int r = x.u + 0x7FFFu + ((x.u >> 16) & 1u);  // round-to-nearest-even
  return (unsigned short)(r >> 16);
}

// -------------------- x : f32 -> bf16 (vectorized) -------------------------
__global__ void cvt_bf16_kernel(const float* __restrict__ src,
                                unsigned short* __restrict__ dst, int n4) {
  int i = blockIdx.x * blockDim.x + threadIdx.x;
  if (i >= n4) return;
  const f32x4 v = *(const f32x4*)(src + (size_t)i * 4);
  ushort4 u = make_ushort4(f2bf(v[0]), f2bf(v[1]), f2bf(v[2]), f2bf(v[3]));
  *(ushort4*)(dst + (size_t)i * 4) = u;
}

// ------ W transpose+convert: dst[(rowOff+n)*2048 + k] = bf16(src[k*N+n]) ----
__global__ void transpose_bf16_kernel(const float* __restrict__ src,
                                      unsigned short* __restrict__ dst,
                                      int N, int rowOff) {
  __shared__ float tile[32][33];
  const int n0 = blockIdx.x * 32, k0 = blockIdx.y * 32;
  const int tx = threadIdx.x & 31, ty = threadIdx.x >> 5;  // 32x8
#pragma unroll
  for (int i = ty; i < 32; i += 8)
    tile[i][tx] = src[(size_t)(k0 + i) * N + (n0 + tx)];
  __syncthreads();
#pragma unroll
  for (int i = ty; i < 32; i += 8)
    dst[(size_t)(rowOff + n0 + i) * 2048 + (k0 + tx)] = f2bf(tile[tx][i]);
}

// -------------------- bf16 MFMA GEMM: C = A * Bt^T --------------------------
// A: [M][K] bf16 row-major, Bt: [N][K] bf16. C: [M][N] f32.
// 128x128 tile, BK=64, 4 waves (2x2), 16x16x32 MFMA, global_load_lds w=16,
// source-side XOR swizzle (rule #21).
__global__ __launch_bounds__(256) void gemm_bf16_kernel(
    const unsigned short* __restrict__ A, const unsigned short* __restrict__ Bt,
    float* __restrict__ C, int K, int N) {
  __shared__ unsigned short As[128 * 64];
  __shared__ unsigned short Bs[128 * 64];
  const int tid = threadIdx.x;
  const int lane = tid & 63, wid = tid >> 6;
  const int m0 = blockIdx.y * 128, n0 = blockIdx.x * 128;
  const int wm = (wid >> 1) * 64, wn = (wid & 1) * 64;
  const int l15 = lane & 15, lg = lane >> 4;

  f32x4 acc[4][4];
#pragma unroll
  for (int i = 0; i < 4; ++i)
#pragma unroll
    for (int j = 0; j < 4; ++j)
#pragma unroll
      for (int c = 0; c < 4; ++c) acc[i][j][c] = 0.0f;

  for (int kt = 0; kt < K; kt += 64) {
    __syncthreads();
#pragma unroll
    for (int it = 0; it < 4; ++it) {
      const int chunk = it * 4 + wid;
      const int gi = chunk * 64 + lane;
      const int r = gi >> 3, sg = gi & 7;
      const int ks = kt + ((sg ^ (r & 7)) << 3);
      __builtin_amdgcn_global_load_lds(AS1C(A + (size_t)(m0 + r) * K + ks),
                                       AS3(&As[chunk * 512]), 16, 0, 0);
      __builtin_amdgcn_global_load_lds(AS1C(Bt + (size_t)(n0 + r) * K + ks),
                                       AS3(&Bs[chunk * 512]), 16, 0, 0);
    }
    __syncthreads();
#pragma unroll
    for (int kk = 0; kk < 2; ++kk) {
      short8 av[4], bv[4];
#pragma unroll
      for (int f = 0; f < 4; ++f) {
        const int ra = wm + f * 16 + l15;
        av[f] = *(const short8*)&As[ra * 64 + ((((kk << 2) | lg) ^ (ra & 7)) << 3)];
        const int rb = wn + f * 16 + l15;
        bv[f] = *(const short8*)&Bs[rb * 64 + ((((kk << 2) | lg) ^ (rb & 7)) << 3)];
      }
#pragma unroll
      for (int fm = 0; fm < 4; ++fm)
#pragma unroll
        for (int fn = 0; fn < 4; ++fn)
          acc[fm][fn] = __builtin_amdgcn_mfma_f32_16x16x32_bf16(
              av[fm], bv[fn], acc[fm][fn], 0, 0, 0);
    }
  }
  const int cr = lg << 2;
#pragma unroll
  for (int fm = 0; fm < 4; ++fm)
#pragma unroll
    for (int fn = 0; fn < 4; ++fn) {
      const size_t base =
          (size_t)(m0 + wm + fm * 16 + cr) * N + (n0 + wn + fn * 16 + l15);
#pragma unroll
      for (int r = 0; r < 4; ++r) C[base + (size_t)r * N] = acc[fm][fn][r];
    }
}

// ------- RoPE + bf16 cast: qkv f32 -> qb [4096][2048] (scaled 1/8), ---------
// -------                      kb [4096][512]                        ---------
__global__ void rope_cvt_kernel(const float* __restrict__ qkv,
                                unsigned short* __restrict__ qb,
                                unsigned short* __restrict__ kb) {
  const int idx = blockIdx.x * 256 + threadIdx.x;  // 4096*1280
  const int m = idx / 1280;
  const int p = idx - m * 1280;
  const int t = m & 1023;
  int i, srcCol;
  bool isQ = (p < 1024);
  if (isQ) { i = p & 31; srcCol = ((p >> 5) << 6) + (i << 1); }
  else { const int pk = p - 1024; i = pk & 31; srcCol = 2048 + ((pk >> 5) << 6) + (i << 1); }
  // inv_freq = 10000^(-i/32) = 2^(-i*log2(10000)/32)
  const float inv = exp2f(-(float)i * 0.41524101186092029f);
  const float ang = (float)t * inv;
  float sv, cv;
  __sincosf(ang, &sv, &cv);
  const float* src = qkv + (size_t)m * 3072 + srcCol;
  const float x1 = src[0], x2 = src[1];
  float o1 = x1 * cv - x2 * sv;
  float o2 = x2 * cv + x1 * sv;
  if (isQ) {
    o1 *= 0.125f; o2 *= 0.125f;  // fold 1/sqrt(D) into Q
    unsigned short* d = qb + (size_t)m * 2048 + srcCol;
    d[0] = f2bf(o1); d[1] = f2bf(o2);
  } else {
    unsigned short* d = kb + (size_t)m * 512 + (srcCol - 2048);
    d[0] = f2bf(o1); d[1] = f2bf(o2);
  }
}

// ------- V transpose: qkv cols 2560.. -> vt [(b*8+kvh)*64 + d][1024 t] ------
__global__ void vt_kernel(const float* __restrict__ qkv,
                          unsigned short* __restrict__ vt) {
  __shared__ float tile[32][33];
  const int z = blockIdx.z;           // b*8+kvh
  const int b = z >> 3, kvh = z & 7;
  const int t0 = blockIdx.x * 32, d0 = blockIdx.y * 32;
  const int tx = threadIdx.x & 31, ty = threadIdx.x >> 5;  // 32x8
#pragma unroll
  for (int i = ty; i < 32; i += 8)
    tile[i][tx] = qkv[((size_t)b * 1024 + t0 + i) * 3072 + 2560 + kvh * 64 + d0 + tx];
  __syncthreads();
#pragma unroll
  for (int i = ty; i < 32; i += 8)
    vt[((size_t)z * 64 + d0 + i) * 1024 + t0 + tx] = f2bf(tile[tx][i]);
}

// -------------------- bf16 MFMA flash attention (causal, GQA 4:1) -----------
// block: (qt, h, b), 4 waves; 64 q-rows x 64-wide kv tiles; 16x16x32 MFMA.
// Wave w owns q-rows [w*16, w*16+16). All LDS tiles [64 rows][64 bf16] with
// granule swizzle g ^= (row&7) applied on the global SOURCE for
// global_load_lds staging and on ds addresses for reads/writes.
__global__ __launch_bounds__(256) void attn_mfma_kernel(
    const unsigned short* __restrict__ qb, const unsigned short* __restrict__ kb,
    const unsigned short* __restrict__ vt, unsigned short* __restrict__ attnb) {
  const int qt = blockIdx.x, h = blockIdx.y, b = blockIdx.z;
  const int kvh = h >> 2;
  __shared__ unsigned short Qs[4096], Ks[4096], Vts[4096], Ps[4096];
  const int tid = threadIdx.x, lane = tid & 63, w = tid >> 6;
  const int l15 = lane & 15, lg = lane >> 4;
  const size_t qrow0 = (size_t)b * 1024 + qt * 64;
  const int rowbase = w * 16 + lg * 4;

  // ---- stage Q tile (rows qrow0.., head h), source-swizzled ----
#pragma unroll
  for (int it = 0; it < 2; ++it) {
    const int chunk = it * 4 + w;
    const int gi = chunk * 64 + lane, r = gi >> 3, sg = gi & 7;
    const int g = sg ^ (r & 7);
    __builtin_amdgcn_global_load_lds(
        AS1C(qb + (qrow0 + r) * 2048 + h * 64 + g * 8),
        AS3(&Qs[chunk * 512]), 16, 0, 0);
  }
  __syncthreads();

  // Q fragments for this wave: rows w*16 + l15, k = kk*32 + lg*8
  short8 qf[2];
#pragma unroll
  for (int kk = 0; kk < 2; ++kk) {
    const int r = w * 16 + l15;
    const int g = ((kk << 2) | lg) ^ (r & 7);
    qf[kk] = *(const short8*)&Qs[r * 64 + g * 8];
  }

  float m_i[4], l_i[4];
  f32x4 oa[4];
#pragma unroll
  for (int r = 0; r < 4; ++r) { m_i[r] = -INFINITY; l_i[r] = 0.f; }
#pragma unroll
  for (int fd = 0; fd < 4; ++fd)
#pragma unroll
    for (int r = 0; r < 4; ++r) oa[fd][r] = 0.f;

  for (int jt = 0; jt <= qt; ++jt) {
    __syncthreads();  // prior PV reads of Ks/Vts complete
    // ---- stage K and Vt tiles ----
#pragma unroll
    for (int it = 0; it < 2; ++it) {
      const int chunk = it * 4 + w;
      const int gi = chunk * 64 + lane, r = gi >> 3, sg = gi & 7;
      const int g = sg ^ (r & 7);
      __builtin_amdgcn_global_load_lds(
          AS1C(kb + ((size_t)b * 1024 + jt * 64 + r) * 512 + kvh * 64 + g * 8),
          AS3(&Ks[chunk * 512]), 16, 0, 0);
      __builtin_amdgcn_global_load_lds(
          AS1C(vt + ((size_t)(b * 8 + kvh) * 64 + r) * 1024 + jt * 64 + g * 8),
          AS3(&Vts[chunk * 512]), 16, 0, 0);
    }
    __syncthreads();

    // ---- S = Q K^T ----
    f32x4 sa[4];
#pragma unroll
    for (int fn = 0; fn < 4; ++fn)
#pragma unroll
      for (int r = 0; r < 4; ++r) sa[fn][r] = 0.f;
#pragma unroll
    for (int kk = 0; kk < 2; ++kk) {
      short8 kf[4];
#pragma unroll
      for (int fn = 0; fn < 4; ++fn) {
        const int rkv = fn * 16 + l15;
        const int g = ((kk << 2) | lg) ^ (rkv & 7);
        kf[fn] = *(const short8*)&Ks[rkv * 64 + g * 8];
      }
#pragma unroll
      for (int fn = 0; fn < 4; ++fn)
        sa[fn] = __builtin_amdgcn_mfma_f32_16x16x32_bf16(qf[kk], kf[fn], sa[fn], 0, 0, 0);
    }

    // ---- online softmax (rows lg*4+r; 16-lane shfl reduce) ----
    const bool diag = (jt == qt);
#pragma unroll
    for (int r = 0; r < 4; ++r) {
      const int row = rowbase + r;
      float rm = -INFINITY;
#pragma unroll
      for (int fn = 0; fn < 4; ++fn) {
        float v = sa[fn][r];
        if (diag && (fn * 16 + l15) > row) v = -INFINITY;
        sa[fn][r] = v;
        rm = fmaxf(rm, v);
      }
      rm = fmaxf(rm, __shfl_xor(rm, 1));
      rm = fmaxf(rm, __shfl_xor(rm, 2));
      rm = fmaxf(rm, __shfl_xor(rm, 4));
      rm = fmaxf(rm, __shfl_xor(rm, 8));
      const float mn = fmaxf(m_i[r], rm);
      const float alpha = __expf(m_i[r] - mn);  // exp(-inf)=0 first tile
      m_i[r] = mn;
      float rs = 0.f;
#pragma unroll
      for (int fn = 0; fn < 4; ++fn) {
        const float pj = __expf(sa[fn][r] - mn);
        sa[fn][r] = pj;
        rs += pj;
      }
      rs += __shfl_xor(rs, 1);
      rs += __shfl_xor(rs, 2);
      rs += __shfl_xor(rs, 4);
      rs += __shfl_xor(rs, 8);
      l_i[r] = l_i[r] * alpha + rs;
#pragma unroll
      for (int fd = 0; fd < 4; ++fd) oa[fd][r] *= alpha;
    }

    // ---- P -> LDS (bf16, swizzled) ----
#pragma unroll
    for (int r = 0; r < 4; ++r) {
      const int prow = rowbase + r;
#pragma unroll
      for (int fn = 0; fn < 4; ++fn) {
        const int col = fn * 16 + l15;
        const int g = (col >> 3) ^ (prow & 7);
        Ps[prow * 64 + g * 8 + (col & 7)] = f2bf(sa[fn][r]);
      }
    }
    __syncthreads();  // P visible (and keeps waves phase-locked)

    // ---- O += P V  (B = Vt rows) ----
#pragma unroll
    for (int kk = 0; kk < 2; ++kk) {
      const int rp = w * 16 + l15;
      const int gp = ((kk << 2) | lg) ^ (rp & 7);
      const short8 pf = *(const short8*)&Ps[rp * 64 + gp * 8];
      short8 vf[4];
#pragma unroll
      for (int fd = 0; fd < 4; ++fd) {
        const int rd = fd * 16 + l15;
        const int g = ((kk << 2) | lg) ^ (rd & 7);
        vf[fd] = *(const short8*)&Vts[rd * 64 + g * 8];
      }
#pragma unroll
      for (int fd = 0; fd < 4; ++fd)
        oa[fd] = __builtin_amdgcn_mfma_f32_16x16x32_bf16(pf, vf[fd], oa[fd], 0, 0, 0);
    }
  }

  // ---- epilogue: normalize, write bf16 ----
#pragma unroll
  for (int r = 0; r < 4; ++r) {
    const float inv = 1.0f / l_i[r];
    const size_t row = qrow0 + rowbase + r;
#pragma unroll
    for (int fd = 0; fd < 4; ++fd)
      attnb[row * 2048 + h * 64 + fd * 16 + l15] = f2bf(oa[fd][r] * inv);
  }
}

// ---------------------------------------------------------------------------
extern "C" void kernel_launch(void* const* d_in, const int* in_sizes, int n_in,
                              void* d_out, int out_size, void* d_ws, size_t ws_size,
                              hipStream_t stream) {
  (void)in_sizes; (void)n_in; (void)out_size; (void)ws_size;
  const float* x  = (const float*)d_in[0];
  const float* Wq = (const float*)d_in[1];
  const float* Wk = (const float*)d_in[2];
  const float* Wv = (const float*)d_in[3];
  const float* Wp = (const float*)d_in[4];

  // workspace layout (100 MiB total):
  //   [0,16M)    xb (x bf16)           -> reused as qb after QKV GEMM
  //   [16M,28M)  Wt ([Wq|Wk|Wv]^T)     -> reused as kb(4M)+vt(4M) after GEMM
  //   [28M,36M)  Wpt (Wp^T)
  //   [36M,84M)  qkv f32 [4096][3072]
  //   [84M,100M) attnb bf16 [4096][2048]
  char* w = (char*)d_ws;
  unsigned short* xb    = (unsigned short*)(w);
  unsigned short* Wt    = (unsigned short*)(w + 16777216);
  unsigned short* Wpt   = (unsigned short*)(w + 29360128);
  float*          qkv   = (float*)(w + 37748736);
  unsigned short* attnb = (unsigned short*)(w + 88080384);
  unsigned short* qb    = (unsigned short*)(w);             // overlays xb
  unsigned short* kbuf  = (unsigned short*)(w + 16777216);  // overlays Wt
  unsigned short* vtb   = (unsigned short*)(w + 20971520);  // overlays Wt+4M
  float* out = (float*)d_out;

  cvt_bf16_kernel<<<8192, 256, 0, stream>>>(x, xb, 2097152);
  transpose_bf16_kernel<<<dim3(64, 64), 256, 0, stream>>>(Wq, Wt, 2048, 0);
  transpose_bf16_kernel<<<dim3(16, 64), 256, 0, stream>>>(Wk, Wt, 512, 2048);
  transpose_bf16_kernel<<<dim3(16, 64), 256, 0, stream>>>(Wv, Wt, 512, 2560);
  transpose_bf16_kernel<<<dim3(64, 64), 256, 0, stream>>>(Wp, Wpt, 2048, 0);

  // QKV projection: [4096][2048] x [2048][3072] -> qkv f32
  gemm_bf16_kernel<<<dim3(24, 32), 256, 0, stream>>>(xb, Wt, qkv, 2048, 3072);
  // RoPE + bf16 pack (q scaled by 1/8), V transpose
  rope_cvt_kernel<<<20480, 256, 0, stream>>>(qkv, qb, kbuf);
  vt_kernel<<<dim3(32, 2, 32), 256, 0, stream>>>(qkv, vtb);
  // flash attention
  attn_mfma_kernel<<<dim3(16, 32, 4), 256, 0, stream>>>(qb, kbuf, vtb, attnb);
  // output projection: [4096][2048] x [2048][2048] -> d_out f32
  gemm_bf16_kernel<<<dim3(16, 32), 256, 0, stream>>>(attnb, Wpt, out, 2048, 2048);
}

// Round 5
// 273.017 us; speedup vs baseline: 4.3909x; 1.0239x over previous
//
#include <hip/hip_runtime.h>

// ---------------------------------------------------------------------------
// SelfAttention fused pipeline for MI355X (gfx950)
//   x(4,1024,2048) f32; Wq(2048,2048) Wk/Wv(2048,512) Wp(2048,2048) f32
//   GEMMs + attention QK^T/PV in bf16 MFMA (fp32 accum), RoPE/softmax in f32.
// ---------------------------------------------------------------------------

typedef __attribute__((ext_vector_type(4))) float f32x4;
typedef __attribute__((ext_vector_type(8))) short short8;

#define AS1C(p) ((const __attribute__((address_space(1))) void*)(p))
#define AS3(p)  ((__attribute__((address_space(3))) void*)(p))

__device__ __forceinline__ unsigned short f2bf(float f) {
  union { float f; unsigned int u; } x; x.f = f;
  unsigned int r = x.u + 0x7FFFu + ((x.u >> 16) & 1u);  // round-to-nearest-even
  return (unsigned short)(r >> 16);
}

// -------------------- x : f32 -> bf16 (vectorized) -------------------------
__global__ void cvt_bf16_kernel(const float* __restrict__ src,
                                unsigned short* __restrict__ dst, int n4) {
  int i = blockIdx.x * blockDim.x + threadIdx.x;
  if (i >= n4) return;
  const f32x4 v = *(const f32x4*)(src + (size_t)i * 4);
  ushort4 u = make_ushort4(f2bf(v[0]), f2bf(v[1]), f2bf(v[2]), f2bf(v[3]));
  *(ushort4*)(dst + (size_t)i * 4) = u;
}

// ------ W transpose+convert: dst[(rowOff+n)*2048 + k] = bf16(src[k*N+n]) ----
__global__ void transpose_bf16_kernel(const float* __restrict__ src,
                                      unsigned short* __restrict__ dst,
                                      int N, int rowOff) {
  __shared__ float tile[32][33];
  const int n0 = blockIdx.x * 32, k0 = blockIdx.y * 32;
  const int tx = threadIdx.x & 31, ty = threadIdx.x >> 5;  // 32x8
#pragma unroll
  for (int i = ty; i < 32; i += 8)
    tile[i][tx] = src[(size_t)(k0 + i) * N + (n0 + tx)];
  __syncthreads();
#pragma unroll
  for (int i = ty; i < 32; i += 8)
    dst[(size_t)(rowOff + n0 + i) * 2048 + (k0 + tx)] = f2bf(tile[tx][i]);
}

// -------------------- bf16 MFMA GEMM: C = A * Bt^T --------------------------
__global__ __launch_bounds__(256) void gemm_bf16_kernel(
    const unsigned short* __restrict__ A, const unsigned short* __restrict__ Bt,
    float* __restrict__ C, int K, int N) {
  __shared__ unsigned short As[128 * 64];
  __shared__ unsigned short Bs[128 * 64];
  const int tid = threadIdx.x;
  const int lane = tid & 63, wid = tid >> 6;
  const int m0 = blockIdx.y * 128, n0 = blockIdx.x * 128;
  const int wm = (wid >> 1) * 64, wn = (wid & 1) * 64;
  const int l15 = lane & 15, lg = lane >> 4;

  f32x4 acc[4][4];
#pragma unroll
  for (int i = 0; i < 4; ++i)
#pragma unroll
    for (int j = 0; j < 4; ++j)
#pragma unroll
      for (int c = 0; c < 4; ++c) acc[i][j][c] = 0.0f;

  for (int kt = 0; kt < K; kt += 64) {
    __syncthreads();
#pragma unroll
    for (int it = 0; it < 4; ++it) {
      const int chunk = it * 4 + wid;
      const int gi = chunk * 64 + lane;
      const int r = gi >> 3, sg = gi & 7;
      const int ks = kt + ((sg ^ (r & 7)) << 3);
      __builtin_amdgcn_global_load_lds(AS1C(A + (size_t)(m0 + r) * K + ks),
                                       AS3(&As[chunk * 512]), 16, 0, 0);
      __builtin_amdgcn_global_load_lds(AS1C(Bt + (size_t)(n0 + r) * K + ks),
                                       AS3(&Bs[chunk * 512]), 16, 0, 0);
    }
    __syncthreads();
#pragma unroll
    for (int kk = 0; kk < 2; ++kk) {
      short8 av[4], bv[4];
#pragma unroll
      for (int f = 0; f < 4; ++f) {
        const int ra = wm + f * 16 + l15;
        av[f] = *(const short8*)&As[ra * 64 + ((((kk << 2) | lg) ^ (ra & 7)) << 3)];
        const int rb = wn + f * 16 + l15;
        bv[f] = *(const short8*)&Bs[rb * 64 + ((((kk << 2) | lg) ^ (rb & 7)) << 3)];
      }
#pragma unroll
      for (int fm = 0; fm < 4; ++fm)
#pragma unroll
        for (int fn = 0; fn < 4; ++fn)
          acc[fm][fn] = __builtin_amdgcn_mfma_f32_16x16x32_bf16(
              av[fm], bv[fn], acc[fm][fn], 0, 0, 0);
    }
  }
  const int cr = lg << 2;
#pragma unroll
  for (int fm = 0; fm < 4; ++fm)
#pragma unroll
    for (int fn = 0; fn < 4; ++fn) {
      const size_t base =
          (size_t)(m0 + wm + fm * 16 + cr) * N + (n0 + wn + fn * 16 + l15);
#pragma unroll
      for (int r = 0; r < 4; ++r) C[base + (size_t)r * N] = acc[fm][fn][r];
    }
}

// ------- RoPE + bf16 cast: qkv f32 -> qb [4096][2048] (scaled 1/8), ---------
// -------                      kb [4096][512]                        ---------
__global__ void rope_cvt_kernel(const float* __restrict__ qkv,
                                unsigned short* __restrict__ qb,
                                unsigned short* __restrict__ kb) {
  const int idx = blockIdx.x * 256 + threadIdx.x;  // 4096*1280
  const int m = idx / 1280;
  const int p = idx - m * 1280;
  const int t = m & 1023;
  int i, srcCol;
  bool isQ = (p < 1024);
  if (isQ) { i = p & 31; srcCol = ((p >> 5) << 6) + (i << 1); }
  else { const int pk = p - 1024; i = pk & 31; srcCol = 2048 + ((pk >> 5) << 6) + (i << 1); }
  const float inv = exp2f(-(float)i * 0.41524101186092029f);
  const float ang = (float)t * inv;
  float sv, cv;
  __sincosf(ang, &sv, &cv);
  const float* src = qkv + (size_t)m * 3072 + srcCol;
  const float x1 = src[0], x2 = src[1];
  float o1 = x1 * cv - x2 * sv;
  float o2 = x2 * cv + x1 * sv;
  if (isQ) {
    o1 *= 0.125f; o2 *= 0.125f;  // fold 1/sqrt(D) into Q
    unsigned short* d = qb + (size_t)m * 2048 + srcCol;
    d[0] = f2bf(o1); d[1] = f2bf(o2);
  } else {
    unsigned short* d = kb + (size_t)m * 512 + (srcCol - 2048);
    d[0] = f2bf(o1); d[1] = f2bf(o2);
  }
}

// ------- V transpose: qkv cols 2560.. -> vt [(b*8+kvh)*64 + d][1024 t] ------
__global__ void vt_kernel(const float* __restrict__ qkv,
                          unsigned short* __restrict__ vt) {
  __shared__ float tile[32][33];
  const int z = blockIdx.z;           // b*8+kvh
  const int b = z >> 3, kvh = z & 7;
  const int t0 = blockIdx.x * 32, d0 = blockIdx.y * 32;
  const int tx = threadIdx.x & 31, ty = threadIdx.x >> 5;  // 32x8
#pragma unroll
  for (int i = ty; i < 32; i += 8)
    tile[i][tx] = qkv[((size_t)b * 1024 + t0 + i) * 3072 + 2560 + kvh * 64 + d0 + tx];
  __syncthreads();
#pragma unroll
  for (int i = ty; i < 32; i += 8)
    vt[((size_t)z * 64 + d0 + i) * 1024 + t0 + tx] = f2bf(tile[tx][i]);
}

// -------------------- bf16 MFMA flash attention (causal, GQA 4:1) -----------
// block: (qt, h, b), 4 waves; 64 q-rows x 64-wide kv tiles; 16x16x32 MFMA.
// Double-buffered K/V staging: prefetch for tile jt+1 issued at top of iter jt,
// drained by the single end-of-iter __syncthreads (implicit vmcnt(0)).
// P round-trip uses R2's verified swizzle scheme and is wave-private (wave w
// writes/reads only rows [w*16, w*16+16)), so no barrier between write & read.
// LDS: one array, integer region offsets (no LDS pointer arrays -> no
// addrspacecast static-init issue). P region ALIASES the Q region.
__global__ __launch_bounds__(256) void attn_mfma_kernel(
    const unsigned short* __restrict__ qb, const unsigned short* __restrict__ kb,
    const unsigned short* __restrict__ vt, unsigned short* __restrict__ attnb) {
  const int qt = blockIdx.x, h = blockIdx.y, b = blockIdx.z;
  const int kvh = h >> 2;
  // regions (shorts): QP [0,4096), K: [4096 + buf*4096), V: [12288 + buf*4096)
  __shared__ unsigned short S[20480];  // 40 KiB
  const int tid = threadIdx.x, lane = tid & 63, w = tid >> 6;
  const int l15 = lane & 15, lg = lane >> 4;
  const size_t qrow0 = (size_t)b * 1024 + qt * 64;
  const int rowbase = w * 16 + lg * 4;

  // staging geometry: wave w covers chunks {w, 4+w}; granule gi=chunk*64+lane
  const int gi0 = w * 64 + lane;
  const int r0 = gi0 >> 3, g0 = (gi0 & 7) ^ (r0 & 7);
  const int gi1 = (4 + w) * 64 + lane;
  const int r1 = gi1 >> 3, g1 = (gi1 & 7) ^ (r1 & 7);

  const unsigned short* kbase = kb + (size_t)b * 1024 * 512 + kvh * 64;
  const unsigned short* vbase = vt + (size_t)(b * 8 + kvh) * 64 * 1024;

#define STAGE_KV(kOff, vOff, jj)                                                    \
  do {                                                                              \
    __builtin_amdgcn_global_load_lds(AS1C(kbase + ((jj) * 64 + r0) * 512 + g0 * 8), \
                                     AS3(&S[(kOff) + w * 512]), 16, 0, 0);          \
    __builtin_amdgcn_global_load_lds(AS1C(kbase + ((jj) * 64 + r1) * 512 + g1 * 8), \
                                     AS3(&S[(kOff) + (4 + w) * 512]), 16, 0, 0);    \
    __builtin_amdgcn_global_load_lds(AS1C(vbase + r0 * 1024 + (jj) * 64 + g0 * 8),  \
                                     AS3(&S[(vOff) + w * 512]), 16, 0, 0);          \
    __builtin_amdgcn_global_load_lds(AS1C(vbase + r1 * 1024 + (jj) * 64 + g1 * 8),  \
                                     AS3(&S[(vOff) + (4 + w) * 512]), 16, 0, 0);    \
  } while (0)

  // ---- prologue: stage Q tile + K/V tile 0 ----
  __builtin_amdgcn_global_load_lds(AS1C(qb + (qrow0 + r0) * 2048 + h * 64 + g0 * 8),
                                   AS3(&S[w * 512]), 16, 0, 0);
  __builtin_amdgcn_global_load_lds(AS1C(qb + (qrow0 + r1) * 2048 + h * 64 + g1 * 8),
                                   AS3(&S[(4 + w) * 512]), 16, 0, 0);
  STAGE_KV(4096, 12288, 0);
  __syncthreads();

  // Q fragments: rows w*16 + l15, k = kk*32 + lg*8 (wave-private band)
  short8 qf[2];
#pragma unroll
  for (int kk = 0; kk < 2; ++kk) {
    const int r = w * 16 + l15;
    const int g = ((kk << 2) | lg) ^ (r & 7);
    qf[kk] = *(const short8*)&S[r * 64 + g * 8];
  }

  float m_i[4], l_i[4];
  f32x4 oa[4];
#pragma unroll
  for (int r = 0; r < 4; ++r) { m_i[r] = -INFINITY; l_i[r] = 0.f; }
#pragma unroll
  for (int fd = 0; fd < 4; ++fd)
#pragma unroll
    for (int r = 0; r < 4; ++r) oa[fd][r] = 0.f;

  for (int jt = 0; jt <= qt; ++jt) {
    const int cur = jt & 1;
    const int kOff = 4096 + cur * 4096;
    const int vOff = 12288 + cur * 4096;
    if (jt < qt) STAGE_KV(4096 + (cur ^ 1) * 4096, 12288 + (cur ^ 1) * 4096, jt + 1);

    // ---- S = Q K^T from K[cur] ----
    f32x4 sa[4];
#pragma unroll
    for (int fn = 0; fn < 4; ++fn)
#pragma unroll
      for (int r = 0; r < 4; ++r) sa[fn][r] = 0.f;
#pragma unroll
    for (int kk = 0; kk < 2; ++kk) {
      short8 kf[4];
#pragma unroll
      for (int fn = 0; fn < 4; ++fn) {
        const int rkv = fn * 16 + l15;
        const int g = ((kk << 2) | lg) ^ (rkv & 7);
        kf[fn] = *(const short8*)&S[kOff + rkv * 64 + g * 8];
      }
      __builtin_amdgcn_s_setprio(1);
#pragma unroll
      for (int fn = 0; fn < 4; ++fn)
        sa[fn] = __builtin_amdgcn_mfma_f32_16x16x32_bf16(qf[kk], kf[fn], sa[fn], 0, 0, 0);
      __builtin_amdgcn_s_setprio(0);
    }

    // ---- online softmax (rows rowbase+r; 16-lane shfl reduce) ----
    const bool diag = (jt == qt);
#pragma unroll
    for (int r = 0; r < 4; ++r) {
      const int row = rowbase + r;
      float rm = -INFINITY;
#pragma unroll
      for (int fn = 0; fn < 4; ++fn) {
        float v = sa[fn][r];
        if (diag && (fn * 16 + l15) > row) v = -INFINITY;
        sa[fn][r] = v;
        rm = fmaxf(rm, v);
      }
      rm = fmaxf(rm, __shfl_xor(rm, 1));
      rm = fmaxf(rm, __shfl_xor(rm, 2));
      rm = fmaxf(rm, __shfl_xor(rm, 4));
      rm = fmaxf(rm, __shfl_xor(rm, 8));
      const float mn = fmaxf(m_i[r], rm);
      const float alpha = __expf(m_i[r] - mn);
      m_i[r] = mn;
      float rs = 0.f;
#pragma unroll
      for (int fn = 0; fn < 4; ++fn) {
        const float pj = __expf(sa[fn][r] - mn);
        sa[fn][r] = pj;
        rs += pj;
      }
      rs += __shfl_xor(rs, 1);
      rs += __shfl_xor(rs, 2);
      rs += __shfl_xor(rs, 4);
      rs += __shfl_xor(rs, 8);
      l_i[r] = l_i[r] * alpha + rs;
#pragma unroll
      for (int fd = 0; fd < 4; ++fd) oa[fd][r] *= alpha;
    }

    // ---- P -> LDS (bf16, R2-verified swizzle; wave-private band in QP) ----
#pragma unroll
    for (int r = 0; r < 4; ++r) {
      const int prow = rowbase + r;
#pragma unroll
      for (int fn = 0; fn < 4; ++fn) {
        const int col = fn * 16 + l15;
        const int g = (col >> 3) ^ (prow & 7);
        S[prow * 64 + g * 8 + (col & 7)] = f2bf(sa[fn][r]);
      }
    }
    // no barrier: wave w reads back only rows it just wrote (compiler orders
    // same-array LDS ops; lgkmcnt inserted automatically)

    // ---- O += P V  (A = P fragment, B = Vt rows from V[cur]) ----
#pragma unroll
    for (int kk = 0; kk < 2; ++kk) {
      const int rp = w * 16 + l15;
      const int gp = ((kk << 2) | lg) ^ (rp & 7);
      const short8 pf = *(const short8*)&S[rp * 64 + gp * 8];
      short8 vf[4];
#pragma unroll
      for (int fd = 0; fd < 4; ++fd) {
        const int rd = fd * 16 + l15;
        const int g = ((kk << 2) | lg) ^ (rd & 7);
        vf[fd] = *(const short8*)&S[vOff + rd * 64 + g * 8];
      }
      __builtin_amdgcn_s_setprio(1);
#pragma unroll
      for (int fd = 0; fd < 4; ++fd)
        oa[fd] = __builtin_amdgcn_mfma_f32_16x16x32_bf16(pf, vf[fd], oa[fd], 0, 0, 0);
      __builtin_amdgcn_s_setprio(0);
    }

    __syncthreads();  // all waves done with buf[cur]; prefetch (vmcnt) drained
  }
#undef STAGE_KV

  // ---- epilogue: normalize, write bf16 ----
#pragma unroll
  for (int r = 0; r < 4; ++r) {
    const float inv = 1.0f / l_i[r];
    const size_t row = qrow0 + rowbase + r;
#pragma unroll
    for (int fd = 0; fd < 4; ++fd)
      attnb[row * 2048 + h * 64 + fd * 16 + l15] = f2bf(oa[fd][r] * inv);
  }
}

// ---------------------------------------------------------------------------
extern "C" void kernel_launch(void* const* d_in, const int* in_sizes, int n_in,
                              void* d_out, int out_size, void* d_ws, size_t ws_size,
                              hipStream_t stream) {
  (void)in_sizes; (void)n_in; (void)out_size; (void)ws_size;
  const float* x  = (const float*)d_in[0];
  const float* Wq = (const float*)d_in[1];
  const float* Wk = (const float*)d_in[2];
  const float* Wv = (const float*)d_in[3];
  const float* Wp = (const float*)d_in[4];

  // workspace layout (100 MiB total):
  //   [0,16M)    xb (x bf16)           -> reused as qb after QKV GEMM
  //   [16M,28M)  Wt ([Wq|Wk|Wv]^T)     -> reused as kb(4M)+vt(4M) after GEMM
  //   [28M,36M)  Wpt (Wp^T)
  //   [36M,84M)  qkv f32 [4096][3072]
  //   [84M,100M) attnb bf16 [4096][2048]
  char* w = (char*)d_ws;
  unsigned short* xb    = (unsigned short*)(w);
  unsigned short* Wt    = (unsigned short*)(w + 16777216);
  unsigned short* Wpt   = (unsigned short*)(w + 29360128);
  float*          qkv   = (float*)(w + 37748736);
  unsigned short* attnb = (unsigned short*)(w + 88080384);
  unsigned short* qb    = (unsigned short*)(w);             // overlays xb
  unsigned short* kbuf  = (unsigned short*)(w + 16777216);  // overlays Wt
  unsigned short* vtb   = (unsigned short*)(w + 20971520);  // overlays Wt+4M
  float* out = (float*)d_out;

  cvt_bf16_kernel<<<8192, 256, 0, stream>>>(x, xb, 2097152);
  transpose_bf16_kernel<<<dim3(64, 64), 256, 0, stream>>>(Wq, Wt, 2048, 0);
  transpose_bf16_kernel<<<dim3(16, 64), 256, 0, stream>>>(Wk, Wt, 512, 2048);
  transpose_bf16_kernel<<<dim3(16, 64), 256, 0, stream>>>(Wv, Wt, 512, 2560);
  transpose_bf16_kernel<<<dim3(64, 64), 256, 0, stream>>>(Wp, Wpt, 2048, 0);

  // QKV projection: [4096][2048] x [2048][3072] -> qkv f32
  gemm_bf16_kernel<<<dim3(24, 32), 256, 0, stream>>>(xb, Wt, qkv, 2048, 3072);
  // RoPE + bf16 pack (q scaled by 1/8), V transpose
  rope_cvt_kernel<<<20480, 256, 0, stream>>>(qkv, qb, kbuf);
  vt_kernel<<<dim3(32, 2, 32), 256, 0, stream>>>(qkv, vtb);
  // flash attention
  attn_mfma_kernel<<<dim3(16, 32, 4), 256, 0, stream>>>(qb, kbuf, vtb, attnb);
  // output projection: [4096][2048] x [2048][2048] -> d_out f32
  gemm_bf16_kernel<<<dim3(16, 32), 256, 0, stream>>>(attnb, Wpt, out, 2048, 2048);
}

// Round 6
// 223.389 us; speedup vs baseline: 5.3664x; 1.2222x over previous
//
#include <hip/hip_runtime.h>
#include <hip/hip_bf16.h>

// ---------------------------------------------------------------------------
// SelfAttention fused pipeline for MI355X (gfx950)
//   x(4,1024,2048) f32; Wq(2048,2048) Wk/Wv(2048,512) Wp(2048,2048) f32
//   GEMMs + attention QK^T/PV in bf16 MFMA (fp32 accum), RoPE/softmax in f32.
// ---------------------------------------------------------------------------

typedef __attribute__((ext_vector_type(4))) float f32x4;
typedef __attribute__((ext_vector_type(8))) short short8;

#define AS1C(p) ((const __attribute__((address_space(1))) void*)(p))
#define AS3(p)  ((__attribute__((address_space(3))) void*)(p))

__device__ __forceinline__ unsigned short f2bf(float f) {
  union { float f; unsigned int u; } x; x.f = f;
  unsigned int r = x.u + 0x7FFFu + ((x.u >> 16) & 1u);  // round-to-nearest-even
  return (unsigned short)(r >> 16);
}

__device__ __forceinline__ unsigned short bfc(float f) {
  return __bfloat16_as_ushort(__float2bfloat16(f));  // HW cvt (1-2 VALU)
}

// -------------------- x : f32 -> bf16 (vectorized) -------------------------
__global__ void cvt_bf16_kernel(const float* __restrict__ src,
                                unsigned short* __restrict__ dst, int n4) {
  int i = blockIdx.x * blockDim.x + threadIdx.x;
  if (i >= n4) return;
  const f32x4 v = *(const f32x4*)(src + (size_t)i * 4);
  ushort4 u = make_ushort4(f2bf(v[0]), f2bf(v[1]), f2bf(v[2]), f2bf(v[3]));
  *(ushort4*)(dst + (size_t)i * 4) = u;
}

// ------ W transpose+convert: dst[(rowOff+n)*2048 + k] = bf16(src[k*N+n]) ----
__global__ void transpose_bf16_kernel(const float* __restrict__ src,
                                      unsigned short* __restrict__ dst,
                                      int N, int rowOff) {
  __shared__ float tile[32][33];
  const int n0 = blockIdx.x * 32, k0 = blockIdx.y * 32;
  const int tx = threadIdx.x & 31, ty = threadIdx.x >> 5;  // 32x8
#pragma unroll
  for (int i = ty; i < 32; i += 8)
    tile[i][tx] = src[(size_t)(k0 + i) * N + (n0 + tx)];
  __syncthreads();
#pragma unroll
  for (int i = ty; i < 32; i += 8)
    dst[(size_t)(rowOff + n0 + i) * 2048 + (k0 + tx)] = f2bf(tile[tx][i]);
}

// -------------------- bf16 MFMA GEMM: C = A * Bt^T --------------------------
__global__ __launch_bounds__(256) void gemm_bf16_kernel(
    const unsigned short* __restrict__ A, const unsigned short* __restrict__ Bt,
    float* __restrict__ C, int K, int N) {
  __shared__ unsigned short As[128 * 64];
  __shared__ unsigned short Bs[128 * 64];
  const int tid = threadIdx.x;
  const int lane = tid & 63, wid = tid >> 6;
  const int m0 = blockIdx.y * 128, n0 = blockIdx.x * 128;
  const int wm = (wid >> 1) * 64, wn = (wid & 1) * 64;
  const int l15 = lane & 15, lg = lane >> 4;

  f32x4 acc[4][4];
#pragma unroll
  for (int i = 0; i < 4; ++i)
#pragma unroll
    for (int j = 0; j < 4; ++j)
#pragma unroll
      for (int c = 0; c < 4; ++c) acc[i][j][c] = 0.0f;

  for (int kt = 0; kt < K; kt += 64) {
    __syncthreads();
#pragma unroll
    for (int it = 0; it < 4; ++it) {
      const int chunk = it * 4 + wid;
      const int gi = chunk * 64 + lane;
      const int r = gi >> 3, sg = gi & 7;
      const int ks = kt + ((sg ^ (r & 7)) << 3);
      __builtin_amdgcn_global_load_lds(AS1C(A + (size_t)(m0 + r) * K + ks),
                                       AS3(&As[chunk * 512]), 16, 0, 0);
      __builtin_amdgcn_global_load_lds(AS1C(Bt + (size_t)(n0 + r) * K + ks),
                                       AS3(&Bs[chunk * 512]), 16, 0, 0);
    }
    __syncthreads();
#pragma unroll
    for (int kk = 0; kk < 2; ++kk) {
      short8 av[4], bv[4];
#pragma unroll
      for (int f = 0; f < 4; ++f) {
        const int ra = wm + f * 16 + l15;
        av[f] = *(const short8*)&As[ra * 64 + ((((kk << 2) | lg) ^ (ra & 7)) << 3)];
        const int rb = wn + f * 16 + l15;
        bv[f] = *(const short8*)&Bs[rb * 64 + ((((kk << 2) | lg) ^ (rb & 7)) << 3)];
      }
#pragma unroll
      for (int fm = 0; fm < 4; ++fm)
#pragma unroll
        for (int fn = 0; fn < 4; ++fn)
          acc[fm][fn] = __builtin_amdgcn_mfma_f32_16x16x32_bf16(
              av[fm], bv[fn], acc[fm][fn], 0, 0, 0);
    }
  }
  const int cr = lg << 2;
#pragma unroll
  for (int fm = 0; fm < 4; ++fm)
#pragma unroll
    for (int fn = 0; fn < 4; ++fn) {
      const size_t base =
          (size_t)(m0 + wm + fm * 16 + cr) * N + (n0 + wn + fn * 16 + l15);
#pragma unroll
      for (int r = 0; r < 4; ++r) C[base + (size_t)r * N] = acc[fm][fn][r];
    }
}

// ------- RoPE + bf16 cast: qkv f32 -> qb [4096][2048] (scaled 1/8), ---------
// -------                      kb [4096][512]                        ---------
__global__ void rope_cvt_kernel(const float* __restrict__ qkv,
                                unsigned short* __restrict__ qb,
                                unsigned short* __restrict__ kb) {
  const int idx = blockIdx.x * 256 + threadIdx.x;  // 4096*1280
  const int m = idx / 1280;
  const int p = idx - m * 1280;
  const int t = m & 1023;
  int i, srcCol;
  bool isQ = (p < 1024);
  if (isQ) { i = p & 31; srcCol = ((p >> 5) << 6) + (i << 1); }
  else { const int pk = p - 1024; i = pk & 31; srcCol = 2048 + ((pk >> 5) << 6) + (i << 1); }
  const float inv = exp2f(-(float)i * 0.41524101186092029f);
  const float ang = (float)t * inv;
  float sv, cv;
  __sincosf(ang, &sv, &cv);
  const float* src = qkv + (size_t)m * 3072 + srcCol;
  const float x1 = src[0], x2 = src[1];
  float o1 = x1 * cv - x2 * sv;
  float o2 = x2 * cv + x1 * sv;
  if (isQ) {
    o1 *= 0.125f; o2 *= 0.125f;  // fold 1/sqrt(D) into Q
    unsigned short* d = qb + (size_t)m * 2048 + srcCol;
    d[0] = f2bf(o1); d[1] = f2bf(o2);
  } else {
    unsigned short* d = kb + (size_t)m * 512 + (srcCol - 2048);
    d[0] = f2bf(o1); d[1] = f2bf(o2);
  }
}

// ------- V transpose: qkv cols 2560.. -> vt [(b*8+kvh)*64 + d][1024 t] ------
__global__ void vt_kernel(const float* __restrict__ qkv,
                          unsigned short* __restrict__ vt) {
  __shared__ float tile[32][33];
  const int z = blockIdx.z;           // b*8+kvh
  const int b = z >> 3, kvh = z & 7;
  const int t0 = blockIdx.x * 32, d0 = blockIdx.y * 32;
  const int tx = threadIdx.x & 31, ty = threadIdx.x >> 5;  // 32x8
#pragma unroll
  for (int i = ty; i < 32; i += 8)
    tile[i][tx] = qkv[((size_t)b * 1024 + t0 + i) * 3072 + 2560 + kvh * 64 + d0 + tx];
  __syncthreads();
#pragma unroll
  for (int i = ty; i < 32; i += 8)
    vt[((size_t)z * 64 + d0 + i) * 1024 + t0 + tx] = f2bf(tile[tx][i]);
}

// -------------------- bf16 MFMA flash attention (causal, GQA 4:1) -----------
// block: (bx, h, b); processes TWO q-tiles {bx, 15-bx} -> uniform 17 KV-tile
// iterations per block (load balance). 4 waves; 16x16x32 MFMA. Double-buffered
// K/V staging pipelines across the q-tile boundary. Row-sum via ones-column
// MFMA (oe accumulates l_i with the same alpha rescaling as O). P round-trip
// uses the R2-verified swizzle, wave-private band aliasing the Q region.
__global__ __launch_bounds__(256) void attn_mfma_kernel(
    const unsigned short* __restrict__ qb, const unsigned short* __restrict__ kb,
    const unsigned short* __restrict__ vt, unsigned short* __restrict__ attnb) {
  const int bx = blockIdx.x, h = blockIdx.y, b = blockIdx.z;
  const int kvh = h >> 2;
  // regions (shorts): QP [0,4096), K: [4096 + buf*4096), V: [12288 + buf*4096)
  __shared__ unsigned short S[20480];  // 40 KiB
  const int tid = threadIdx.x, lane = tid & 63, w = tid >> 6;
  const int l15 = lane & 15, lg = lane >> 4;
  const int rowbase = w * 16 + lg * 4;

  // staging geometry: wave w covers chunks {w, 4+w}; granule gi=chunk*64+lane
  const int gi0 = w * 64 + lane;
  const int r0 = gi0 >> 3, g0 = (gi0 & 7) ^ (r0 & 7);
  const int gi1 = (4 + w) * 64 + lane;
  const int r1 = gi1 >> 3, g1 = (gi1 & 7) ^ (r1 & 7);

  const unsigned short* kbase = kb + (size_t)b * 1024 * 512 + kvh * 64;
  const unsigned short* vbase = vt + (size_t)(b * 8 + kvh) * 64 * 1024;

#define STAGE_KV(kOff, vOff, jj)                                                    \
  do {                                                                              \
    __builtin_amdgcn_global_load_lds(AS1C(kbase + ((jj) * 64 + r0) * 512 + g0 * 8), \
                                     AS3(&S[(kOff) + w * 512]), 16, 0, 0);          \
    __builtin_amdgcn_global_load_lds(AS1C(kbase + ((jj) * 64 + r1) * 512 + g1 * 8), \
                                     AS3(&S[(kOff) + (4 + w) * 512]), 16, 0, 0);    \
    __builtin_amdgcn_global_load_lds(AS1C(vbase + r0 * 1024 + (jj) * 64 + g0 * 8),  \
                                     AS3(&S[(vOff) + w * 512]), 16, 0, 0);          \
    __builtin_amdgcn_global_load_lds(AS1C(vbase + r1 * 1024 + (jj) * 64 + g1 * 8),  \
                                     AS3(&S[(vOff) + (4 + w) * 512]), 16, 0, 0);    \
  } while (0)

#define STAGE_Q(qt)                                                                     \
  do {                                                                                  \
    const size_t qr_ = (size_t)b * 1024 + (qt) * 64;                                    \
    __builtin_amdgcn_global_load_lds(AS1C(qb + (qr_ + r0) * 2048 + h * 64 + g0 * 8),    \
                                     AS3(&S[w * 512]), 16, 0, 0);                       \
    __builtin_amdgcn_global_load_lds(AS1C(qb + (qr_ + r1) * 2048 + h * 64 + g1 * 8),    \
                                     AS3(&S[(4 + w) * 512]), 16, 0, 0);                 \
  } while (0)

  const int qts0 = bx, qts1 = 15 - bx;

  short8 ones;
#pragma unroll
  for (int i = 0; i < 8; ++i) ones[i] = (short)0x3F80;  // bf16 1.0

  // ---- prologue: stage Q tile A + K/V tile 0 ----
  STAGE_Q(qts0);
  STAGE_KV(4096, 12288, 0);
  __syncthreads();

  int g = 0;  // global tile counter (buffer parity = g&1)
  for (int sub = 0; sub < 2; ++sub) {
    const int qtc = sub ? qts1 : qts0;
    const size_t qrow0 = (size_t)b * 1024 + qtc * 64;

    // Q fragments: rows w*16 + l15, k = kk*32 + lg*8 (wave-private band)
    short8 qf[2];
#pragma unroll
    for (int kk = 0; kk < 2; ++kk) {
      const int r = w * 16 + l15;
      const int gq = ((kk << 2) | lg) ^ (r & 7);
      qf[kk] = *(const short8*)&S[r * 64 + gq * 8];
    }

    float m_i[4];
    f32x4 oa[4], oe;
#pragma unroll
    for (int r = 0; r < 4; ++r) { m_i[r] = -INFINITY; oe[r] = 0.f; }
#pragma unroll
    for (int fd = 0; fd < 4; ++fd)
#pragma unroll
      for (int r = 0; r < 4; ++r) oa[fd][r] = 0.f;

    for (int j = 0; j <= qtc; ++j, ++g) {
      const int cur = g & 1;
      const int kOff = 4096 + cur * 4096;
      const int vOff = 12288 + cur * 4096;
      if (g < 16) {  // prefetch next global tile (crosses sub boundary)
        const int nj = (g + 1 <= qts0) ? g + 1 : g - qts0;
        STAGE_KV(4096 + (cur ^ 1) * 4096, 12288 + (cur ^ 1) * 4096, nj);
      }

      // ---- S = Q K^T from K[cur] ----
      f32x4 sa[4];
#pragma unroll
      for (int fn = 0; fn < 4; ++fn)
#pragma unroll
        for (int r = 0; r < 4; ++r) sa[fn][r] = 0.f;
#pragma unroll
      for (int kk = 0; kk < 2; ++kk) {
        short8 kf[4];
#pragma unroll
        for (int fn = 0; fn < 4; ++fn) {
          const int rkv = fn * 16 + l15;
          const int gk = ((kk << 2) | lg) ^ (rkv & 7);
          kf[fn] = *(const short8*)&S[kOff + rkv * 64 + gk * 8];
        }
        __builtin_amdgcn_s_setprio(1);
#pragma unroll
        for (int fn = 0; fn < 4; ++fn)
          sa[fn] = __builtin_amdgcn_mfma_f32_16x16x32_bf16(qf[kk], kf[fn], sa[fn], 0, 0, 0);
        __builtin_amdgcn_s_setprio(0);
      }

      // ---- online softmax: max only (sum comes from ones-MFMA) ----
      const bool diag = (j == qtc);
#pragma unroll
      for (int r = 0; r < 4; ++r) {
        const int row = rowbase + r;
        if (diag) {
#pragma unroll
          for (int fn = 0; fn < 4; ++fn)
            if ((fn * 16 + l15) > row) sa[fn][r] = -INFINITY;
        }
        float rm = fmaxf(fmaxf(sa[0][r], sa[1][r]), fmaxf(sa[2][r], sa[3][r]));
        rm = fmaxf(rm, __shfl_xor(rm, 1));
        rm = fmaxf(rm, __shfl_xor(rm, 2));
        rm = fmaxf(rm, __shfl_xor(rm, 4));
        rm = fmaxf(rm, __shfl_xor(rm, 8));
        const float mn = fmaxf(m_i[r], rm);
        const float alpha = __expf(m_i[r] - mn);  // exp(-inf)=0 first tile
        m_i[r] = mn;
#pragma unroll
        for (int fn = 0; fn < 4; ++fn)
          sa[fn][r] = __expf(sa[fn][r] - mn);
        oe[r] *= alpha;
#pragma unroll
        for (int fd = 0; fd < 4; ++fd) oa[fd][r] *= alpha;
      }

      // ---- P -> LDS (bf16, R2-verified swizzle; wave-private band in QP) ----
#pragma unroll
      for (int r = 0; r < 4; ++r) {
        const int prow = rowbase + r;
#pragma unroll
        for (int fn = 0; fn < 4; ++fn) {
          const int col = fn * 16 + l15;
          const int gp = (col >> 3) ^ (prow & 7);
          S[prow * 64 + gp * 8 + (col & 7)] = bfc(sa[fn][r]);
        }
      }
      // no barrier: wave w reads back only rows it just wrote

      // ---- O += P V ; row-sum += P * 1  (V from V[cur]) ----
#pragma unroll
      for (int kk = 0; kk < 2; ++kk) {
        const int rp = w * 16 + l15;
        const int gp = ((kk << 2) | lg) ^ (rp & 7);
        const short8 pf = *(const short8*)&S[rp * 64 + gp * 8];
        short8 vf[4];
#pragma unroll
        for (int fd = 0; fd < 4; ++fd) {
          const int rd = fd * 16 + l15;
          const int gv = ((kk << 2) | lg) ^ (rd & 7);
          vf[fd] = *(const short8*)&S[vOff + rd * 64 + gv * 8];
        }
        __builtin_amdgcn_s_setprio(1);
#pragma unroll
        for (int fd = 0; fd < 4; ++fd)
          oa[fd] = __builtin_amdgcn_mfma_f32_16x16x32_bf16(pf, vf[fd], oa[fd], 0, 0, 0);
        oe = __builtin_amdgcn_mfma_f32_16x16x32_bf16(pf, ones, oe, 0, 0, 0);
        __builtin_amdgcn_s_setprio(0);
      }

      __syncthreads();  // all waves done with buf[cur]; prefetch drained
    }

    // ---- epilogue: normalize (l_i == oe[r], present in every lane) ----
#pragma unroll
    for (int r = 0; r < 4; ++r) {
      const float inv = 1.0f / oe[r];
      const size_t row = qrow0 + rowbase + r;
#pragma unroll
      for (int fd = 0; fd < 4; ++fd)
        attnb[row * 2048 + h * 64 + fd * 16 + l15] = f2bf(oa[fd][r] * inv);
    }

    if (sub == 0) {
      STAGE_Q(qts1);      // overwrite QP region with Q tile B
      __syncthreads();    // visible to all waves (B's KV tile 0 already staged)
    }
  }
#undef STAGE_KV
#undef STAGE_Q
}

// ---------------------------------------------------------------------------
extern "C" void kernel_launch(void* const* d_in, const int* in_sizes, int n_in,
                              void* d_out, int out_size, void* d_ws, size_t ws_size,
                              hipStream_t stream) {
  (void)in_sizes; (void)n_in; (void)out_size; (void)ws_size;
  const float* x  = (const float*)d_in[0];
  const float* Wq = (const float*)d_in[1];
  const float* Wk = (const float*)d_in[2];
  const float* Wv = (const float*)d_in[3];
  const float* Wp = (const float*)d_in[4];

  // workspace layout (100 MiB total):
  //   [0,16M)    xb (x bf16)           -> reused as qb after QKV GEMM
  //   [16M,28M)  Wt ([Wq|Wk|Wv]^T)     -> reused as kb(4M)+vt(4M) after GEMM
  //   [28M,36M)  Wpt (Wp^T)
  //   [36M,84M)  qkv f32 [4096][3072]
  //   [84M,100M) attnb bf16 [4096][2048]
  char* w = (char*)d_ws;
  unsigned short* xb    = (unsigned short*)(w);
  unsigned short* Wt    = (unsigned short*)(w + 16777216);
  unsigned short* Wpt   = (unsigned short*)(w + 29360128);
  float*          qkv   = (float*)(w + 37748736);
  unsigned short* attnb = (unsigned short*)(w + 88080384);
  unsigned short* qb    = (unsigned short*)(w);             // overlays xb
  unsigned short* kbuf  = (unsigned short*)(w + 16777216);  // overlays Wt
  unsigned short* vtb   = (unsigned short*)(w + 20971520);  // overlays Wt+4M
  float* out = (float*)d_out;

  cvt_bf16_kernel<<<8192, 256, 0, stream>>>(x, xb, 2097152);
  transpose_bf16_kernel<<<dim3(64, 64), 256, 0, stream>>>(Wq, Wt, 2048, 0);
  transpose_bf16_kernel<<<dim3(16, 64), 256, 0, stream>>>(Wk, Wt, 512, 2048);
  transpose_bf16_kernel<<<dim3(16, 64), 256, 0, stream>>>(Wv, Wt, 512, 2560);
  transpose_bf16_kernel<<<dim3(64, 64), 256, 0, stream>>>(Wp, Wpt, 2048, 0);

  // QKV projection: [4096][2048] x [2048][3072] -> qkv f32
  gemm_bf16_kernel<<<dim3(24, 32), 256, 0, stream>>>(xb, Wt, qkv, 2048, 3072);
  // RoPE + bf16 pack (q scaled by 1/8), V transpose
  rope_cvt_kernel<<<20480, 256, 0, stream>>>(qkv, qb, kbuf);
  vt_kernel<<<dim3(32, 2, 32), 256, 0, stream>>>(qkv, vtb);
  // flash attention (paired q-tiles: uniform 17 tiles/block)
  attn_mfma_kernel<<<dim3(8, 32, 4), 256, 0, stream>>>(qb, kbuf, vtb, attnb);
  // output projection: [4096][2048] x [2048][2048] -> d_out f32
  gemm_bf16_kernel<<<dim3(16, 32), 256, 0, stream>>>(attnb, Wpt, out, 2048, 2048);
}